// Round 1
// baseline (1405.343 us; speedup 1.0000x reference)
//
#include <hip/hip_runtime.h>
#include <cstdint>
#include <cstddef>

#define N_NODES 50000
#define EPS_BN 1e-5f
#define NEG 0.2f

// ---------- helpers ----------
static __device__ __forceinline__ unsigned encf(float f) {
    unsigned u = __float_as_uint(f);
    return (u & 0x80000000u) ? ~u : (u | 0x80000000u);
}
static __device__ __forceinline__ float decf(unsigned v) {
    return (v & 0x80000000u) ? __uint_as_float(v ^ 0x80000000u)
                             : __uint_as_float(~v);
}

// ---------- GEMM: C[M,Nc] = A[M,K] @ B[K,Nc], fp32 SIMT 64x64x16, 4x4/thread ----------
__global__ __launch_bounds__(256) void gemm_tile(
    const float* __restrict__ A, const float* __restrict__ B,
    float* __restrict__ C, int M, int K, int Nc) {
    __shared__ float As[16][64];
    __shared__ float Bs[16][64];
    const int t = threadIdx.x;
    const int m0 = blockIdx.y * 64, n0 = blockIdx.x * 64;
    const int tm = (t & 15) * 4;      // m offset within tile
    const int tn = (t >> 4) * 4;      // n offset within tile
    const int ar = t >> 2, kq = (t & 3) * 4;   // A staging: row, k-quad
    const int br = t >> 4, bc = (t & 15) * 4;  // B staging: k-row, col-quad
    float acc[4][4] = {};
    for (int k0 = 0; k0 < K; k0 += 16) {
        float4 av = make_float4(0.f, 0.f, 0.f, 0.f);
        const int arow = m0 + ar;
        if (arow < M) av = *(const float4*)&A[(size_t)arow * K + k0 + kq];
        const float4 bv = *(const float4*)&B[(size_t)(k0 + br) * Nc + n0 + bc];
        __syncthreads();
        As[kq + 0][ar] = av.x; As[kq + 1][ar] = av.y;
        As[kq + 2][ar] = av.z; As[kq + 3][ar] = av.w;
        *(float4*)&Bs[br][bc] = bv;
        __syncthreads();
#pragma unroll
        for (int k = 0; k < 16; ++k) {
            const float4 a4 = *(const float4*)&As[k][tm];
            const float4 b4 = *(const float4*)&Bs[k][tn];
            acc[0][0] += a4.x * b4.x; acc[0][1] += a4.x * b4.y;
            acc[0][2] += a4.x * b4.z; acc[0][3] += a4.x * b4.w;
            acc[1][0] += a4.y * b4.x; acc[1][1] += a4.y * b4.y;
            acc[1][2] += a4.y * b4.z; acc[1][3] += a4.y * b4.w;
            acc[2][0] += a4.z * b4.x; acc[2][1] += a4.z * b4.y;
            acc[2][2] += a4.z * b4.z; acc[2][3] += a4.z * b4.w;
            acc[3][0] += a4.w * b4.x; acc[3][1] += a4.w * b4.y;
            acc[3][2] += a4.w * b4.z; acc[3][3] += a4.w * b4.w;
        }
    }
#pragma unroll
    for (int i = 0; i < 4; ++i) {
        const int row = m0 + tm + i;
        if (row < M) {
            float4 o = make_float4(acc[i][0], acc[i][1], acc[i][2], acc[i][3]);
            *(float4*)&C[(size_t)row * Nc + n0 + tn] = o;
        }
    }
}

// ---------- per-node attention scores s,d : [N,H] ----------
template <int H>
__global__ __launch_bounds__(128) void scores_kernel(
    const float* __restrict__ h, const float* __restrict__ a_src,
    const float* __restrict__ a_dst, float* __restrict__ s,
    float* __restrict__ d) {
    const int n = blockIdx.x, t = threadIdx.x;
    if (t < 32 * H) {
        const int head = t >> 5;
        const int c0 = (t & 31) * 4;
        const float4 hv = *(const float4*)&h[(size_t)n * (H * 128) + head * 128 + c0];
        const float4 as = *(const float4*)&a_src[head * 128 + c0];
        const float4 ad = *(const float4*)&a_dst[head * 128 + c0];
        float ps = hv.x * as.x + hv.y * as.y + hv.z * as.z + hv.w * as.w;
        float pd = hv.x * ad.x + hv.y * ad.y + hv.z * ad.z + hv.w * ad.w;
#pragma unroll
        for (int m = 16; m >= 1; m >>= 1) {
            ps += __shfl_xor(ps, m, 32);
            pd += __shfl_xor(pd, m, 32);
        }
        if ((t & 31) == 0) {
            s[n * H + head] = ps;
            d[n * H + head] = pd;
        }
    }
}

// ---------- CSR build ----------
__global__ void edge_hist(const int* __restrict__ ei, int E, int* __restrict__ cnt) {
    const int k = blockIdx.x * blockDim.x + threadIdx.x;
    const int ET = E + N_NODES;
    if (k < ET) {
        const int dstn = (k < E) ? ei[E + k] : (k - E);
        atomicAdd(&cnt[dstn], 1);
    }
}

__global__ __launch_bounds__(1024) void scan_kernel(
    const int* __restrict__ cnt, int* __restrict__ rowptr, int n) {
    __shared__ int buf[1024];
    __shared__ int carry;
    const int t = threadIdx.x;
    if (t == 0) { carry = 0; rowptr[0] = 0; }
    __syncthreads();
    for (int base = 0; base < n; base += 1024) {
        const int i = base + t;
        int v = (i < n) ? cnt[i] : 0;
        buf[t] = v;
        __syncthreads();
        for (int off = 1; off < 1024; off <<= 1) {
            int add = (t >= off) ? buf[t - off] : 0;
            __syncthreads();
            buf[t] += add;
            __syncthreads();
        }
        if (i < n) rowptr[i + 1] = carry + buf[t];
        __syncthreads();
        if (t == 0) carry += buf[1023];
        __syncthreads();
    }
}

__global__ void copy_int(const int* __restrict__ a, int* __restrict__ b, int n) {
    const int i = blockIdx.x * blockDim.x + threadIdx.x;
    if (i < n) b[i] = a[i];
}

__global__ void edge_scatter(const int* __restrict__ ei, int E,
                             int* __restrict__ cursor, int* __restrict__ col) {
    const int k = blockIdx.x * blockDim.x + threadIdx.x;
    const int ET = E + N_NODES;
    if (k < ET) {
        const int srcn = (k < E) ? ei[k] : (k - E);
        const int dstn = (k < E) ? ei[E + k] : (k - E);
        const int p = atomicAdd(&cursor[dstn], 1);
        col[p] = srcn;
    }
}

// ---------- segment max of edge scores ----------
template <int H>
__global__ void edge_max(const int* __restrict__ ei, int E,
                         const float* __restrict__ s, const float* __restrict__ d,
                         unsigned* __restrict__ emax) {
    const int k = blockIdx.x * blockDim.x + threadIdx.x;
    const int ET = E + N_NODES;
    if (k >= ET) return;
    const int srcn = (k < E) ? ei[k] : (k - E);
    const int dstn = (k < E) ? ei[E + k] : (k - E);
#pragma unroll
    for (int hh = 0; hh < H; ++hh) {
        float e = s[srcn * H + hh] + d[dstn * H + hh];
        e = (e > 0.f) ? e : NEG * e;
        atomicMax(&emax[dstn * H + hh], encf(e));
    }
}

// ---------- aggregation: one block per destination node ----------
template <int H>
__global__ __launch_bounds__(128) void aggregate(
    const float* __restrict__ h, const float* __restrict__ s,
    const float* __restrict__ dsc, const unsigned* __restrict__ emax,
    const int* __restrict__ rowptr, const int* __restrict__ col,
    const float* __restrict__ bias, float* __restrict__ y) {
    constexpr int HC = H * 128;
    constexpr int VEC = HC / 128;  // 4 for H=4, 1 for H=1
    const int n = blockIdx.x, t = threadIdx.x;
    const int base = t * VEC;
    const int head = base >> 7;
    const float em = decf(emax[n * H + head]);
    const float dn = dsc[n * H + head];
    float acc[VEC];
#pragma unroll
    for (int v = 0; v < VEC; ++v) acc[v] = 0.f;
    float den = 0.f;
    const int rs = rowptr[n], re = rowptr[n + 1];
    for (int j = rs; j < re; ++j) {
        const int srcn = col[j];
        float e = s[srcn * H + head] + dn;
        e = (e > 0.f) ? e : NEG * e;
        const float ex = __expf(e - em);
        den += ex;
        const float* hp = &h[(size_t)srcn * HC + base];
        if constexpr (VEC == 4) {
            const float4 hv = *(const float4*)hp;
            acc[0] += ex * hv.x; acc[1] += ex * hv.y;
            acc[2] += ex * hv.z; acc[3] += ex * hv.w;
        } else {
            acc[0] += ex * hp[0];
        }
    }
    const float inv = 1.f / (den + 1e-16f);
    if constexpr (H == 1) {
        y[(size_t)n * 128 + t] = acc[0] * inv + bias[t];
    } else {
        __shared__ float sh[512];
#pragma unroll
        for (int v = 0; v < VEC; ++v) sh[base + v] = acc[v] * inv;
        __syncthreads();
        if (t < 32) {
            const int c0 = t * 4;
#pragma unroll
            for (int v = 0; v < 4; ++v) {
                const float m = (sh[c0 + v] + sh[128 + c0 + v] +
                                 sh[256 + c0 + v] + sh[384 + c0 + v]) * 0.25f;
                y[(size_t)n * 128 + c0 + v] = m + bias[c0 + v];
            }
        }
    }
}

// ---------- BatchNorm ----------
__global__ __launch_bounds__(256) void bn_stats1(
    const float* __restrict__ y, float* __restrict__ partial, int nblocks) {
    const int b = blockIdx.x, t = threadIdx.x;
    const int c = t & 127;
    float sum = 0.f, sq = 0.f;
    for (int r = b * 2 + (t >> 7); r < N_NODES; r += nblocks * 2) {
        const float v = y[(size_t)r * 128 + c];
        sum += v;
        sq += v * v;
    }
    __shared__ float s1[256], s2[256];
    s1[t] = sum; s2[t] = sq;
    __syncthreads();
    if (t < 128) {
        partial[(size_t)b * 256 + c] = s1[t] + s1[t + 128];
        partial[(size_t)b * 256 + 128 + c] = s2[t] + s2[t + 128];
    }
}

__global__ __launch_bounds__(128) void bn_stats2(
    const float* __restrict__ partial, int nblocks,
    const float* __restrict__ gamma, const float* __restrict__ beta,
    float* __restrict__ stats) {
    const int c = threadIdx.x;
    float S = 0.f, Q = 0.f;
    for (int b = 0; b < nblocks; ++b) {
        S += partial[(size_t)b * 256 + c];
        Q += partial[(size_t)b * 256 + 128 + c];
    }
    const float mu = S / (float)N_NODES;
    const float var = Q / (float)N_NODES - mu * mu;
    const float sc = gamma[c] * rsqrtf(var + EPS_BN);
    stats[c] = sc;
    stats[128 + c] = beta[c] - mu * sc;
}

__global__ void bn_apply(const float* __restrict__ y,
                         const float* __restrict__ stats,
                         float* __restrict__ out, int relu) {
    const int i = blockIdx.x * blockDim.x + threadIdx.x;
    if (i < N_NODES * 128) {
        const int c = i & 127;
        float v = y[i] * stats[c] + stats[128 + c];
        if (relu) v = fmaxf(v, 0.f);
        out[i] = v;
    }
}

// ---------- launch ----------
extern "C" void kernel_launch(void* const* d_in, const int* in_sizes, int n_in,
                              void* d_out, int out_size, void* d_ws, size_t ws_size,
                              hipStream_t stream) {
    const float* x = (const float*)d_in[0];
    const int* ei = (const int*)d_in[1];
    const int E = in_sizes[1] / 2;
    const int ET = E + N_NODES;

    const float* W[3]    = {(const float*)d_in[2], (const float*)d_in[8],  (const float*)d_in[14]};
    const float* ASRC[3] = {(const float*)d_in[3], (const float*)d_in[9],  (const float*)d_in[15]};
    const float* ADST[3] = {(const float*)d_in[4], (const float*)d_in[10], (const float*)d_in[16]};
    const float* BIAS[3] = {(const float*)d_in[5], (const float*)d_in[11], (const float*)d_in[17]};
    const float* GAM[3]  = {(const float*)d_in[6], (const float*)d_in[12], (const float*)d_in[18]};
    const float* BET[3]  = {(const float*)d_in[7], (const float*)d_in[13], (const float*)d_in[19]};

    char* base = (char*)d_ws;
    auto alloc = [&](size_t bytes) {
        char* p = base;
        base += (bytes + 255) & ~(size_t)255;
        return p;
    };
    float*    h       = (float*)alloc((size_t)N_NODES * 512 * 4);
    float*    X       = (float*)alloc((size_t)N_NODES * 128 * 4);
    float*    y       = (float*)alloc((size_t)N_NODES * 128 * 4);
    float*    s       = (float*)alloc((size_t)N_NODES * 4 * 4);
    float*    dsc     = (float*)alloc((size_t)N_NODES * 4 * 4);
    unsigned* emax    = (unsigned*)alloc((size_t)N_NODES * 4 * 4);
    int*      rowptr  = (int*)alloc((size_t)(N_NODES + 1) * 4);
    int*      col     = (int*)alloc((size_t)ET * 4);
    int*      cnt     = (int*)alloc((size_t)N_NODES * 4);
    int*      cursor  = (int*)alloc((size_t)N_NODES * 4);
    float*    partial = (float*)alloc((size_t)256 * 256 * 4);
    float*    stats   = (float*)alloc((size_t)256 * 4);
    if ((size_t)(base - (char*)d_ws) > ws_size) return;  // insufficient workspace

    const int eb = (ET + 255) / 256;

    // --- CSR build (same every call) ---
    hipMemsetAsync(cnt, 0, (size_t)N_NODES * 4, stream);
    edge_hist<<<eb, 256, 0, stream>>>(ei, E, cnt);
    scan_kernel<<<1, 1024, 0, stream>>>(cnt, rowptr, N_NODES);
    copy_int<<<(N_NODES + 255) / 256, 256, 0, stream>>>(rowptr, cursor, N_NODES);
    edge_scatter<<<eb, 256, 0, stream>>>(ei, E, cursor, col);

    const int Hs[3]  = {4, 4, 1};
    const int Kin[3] = {256, 128, 128};

    const float* layer_in = x;
    for (int L = 0; L < 3; ++L) {
        const int H = Hs[L], K = Kin[L], Nc = H * 128;
        dim3 ggrid(Nc / 64, (N_NODES + 63) / 64);
        gemm_tile<<<ggrid, 256, 0, stream>>>(layer_in, W[L], h, N_NODES, K, Nc);

        hipMemsetAsync(emax, 0, (size_t)N_NODES * H * 4, stream);
        if (H == 4) {
            scores_kernel<4><<<N_NODES, 128, 0, stream>>>(h, ASRC[L], ADST[L], s, dsc);
            edge_max<4><<<eb, 256, 0, stream>>>(ei, E, s, dsc, emax);
            aggregate<4><<<N_NODES, 128, 0, stream>>>(h, s, dsc, emax, rowptr, col, BIAS[L], y);
        } else {
            scores_kernel<1><<<N_NODES, 128, 0, stream>>>(h, ASRC[L], ADST[L], s, dsc);
            edge_max<1><<<eb, 256, 0, stream>>>(ei, E, s, dsc, emax);
            aggregate<1><<<N_NODES, 128, 0, stream>>>(h, s, dsc, emax, rowptr, col, BIAS[L], y);
        }

        bn_stats1<<<256, 256, 0, stream>>>(y, partial, 256);
        bn_stats2<<<1, 128, 0, stream>>>(partial, 256, GAM[L], BET[L], stats);

        float* outp = (L == 2) ? (float*)d_out : X;
        bn_apply<<<(N_NODES * 128 + 255) / 256, 256, 0, stream>>>(y, stats, outp, (L < 2) ? 1 : 0);
        layer_in = X;
    }
}

// Round 2
// 885.531 us; speedup vs baseline: 1.5870x; 1.5870x over previous
//
#include <hip/hip_runtime.h>
#include <cstdint>
#include <cstddef>

#define N_NODES 50000
#define M_PAD   50176   // 392 * 128
#define EPS_BN  1e-5f
#define NEG     0.2f

typedef __attribute__((ext_vector_type(8))) short bf16x8;
typedef __attribute__((ext_vector_type(4))) float f32x4;

// ---------- bf16 helpers ----------
static __device__ __forceinline__ ushort f2bf(float f) {
    unsigned u = __float_as_uint(f);
    unsigned r = (u + 0x7FFFu + ((u >> 16) & 1u)) >> 16;   // RNE
    return (ushort)r;
}
static __device__ __forceinline__ float bf2f(ushort b) {
    return __uint_as_float(((unsigned)b) << 16);
}

// ---------- input conversion: x fp32 [N,256] -> bf16 padded [M_PAD,256] ----------
__global__ void conv_x(const float* __restrict__ x, ushort* __restrict__ out) {
    const int i = blockIdx.x * 256 + threadIdx.x;
    const int e0 = i * 4;
    if (e0 >= M_PAD * 256) return;
    const int row = e0 >> 8;
    ushort4 o;
    if (row < N_NODES) {
        const float4 v = *(const float4*)&x[e0];
        o = make_ushort4(f2bf(v.x), f2bf(v.y), f2bf(v.z), f2bf(v.w));
    } else {
        o = make_ushort4(0, 0, 0, 0);
    }
    *(ushort4*)&out[e0] = o;
}

// ---------- weight convert + transpose: W fp32 [K,Nc] -> Wt bf16 [Nc,K] ----------
__global__ void convT(const float* __restrict__ W, ushort* __restrict__ Wt,
                      int K, int Nc) {
    const int i = blockIdx.x * 256 + threadIdx.x;
    if (i < K * Nc) {
        const int k = i / Nc, n = i - k * Nc;
        Wt[(size_t)n * K + k] = f2bf(W[i]);
    }
}

// ---------- MFMA GEMM: C[M_PAD,Nc] = A[M_PAD,K] * Bt[Nc,K]^T, all bf16, fp32 acc ----------
// tile: BM=128, BN=64, BK=32; 4 waves; wave w -> rows [w*32, w*32+32)
__global__ __launch_bounds__(256) void gemm_bf16(
    const ushort* __restrict__ A, const ushort* __restrict__ Bt,
    ushort* __restrict__ C, int K, int Nc) {
    __shared__ ushort As[128 * 32];
    __shared__ ushort Bs[64 * 32];
    const int t = threadIdx.x;
    const int wave = t >> 6, lane = t & 63;
    const int quad = lane >> 4, l16 = lane & 15;
    const int m0 = blockIdx.y * 128, n0 = blockIdx.x * 64;

    // staging: chunk q = 8 ushorts (16B); As chunk t -> row t>>2, col (t&3)*8 (== elem t*8)
    const int aRow = t >> 2, aCol = (t & 3) * 8;
    const ushort* aG0 = A + (size_t)(m0 + aRow) * K + aCol;
    const ushort* aG1 = A + (size_t)(m0 + 64 + aRow) * K + aCol;
    const ushort* bG  = Bt + (size_t)(n0 + aRow) * K + aCol;

    // fragment offsets in LDS (elements)
    const int aOff0 = (wave * 32 + l16) * 32 + quad * 8;
    const int aOff1 = aOff0 + 16 * 32;
    const int bOff  = l16 * 32 + quad * 8;

    f32x4 acc[2][4] = {};
    for (int k0 = 0; k0 < K; k0 += 32) {
        const uint4 a0 = *(const uint4*)(aG0 + k0);
        const uint4 a1 = *(const uint4*)(aG1 + k0);
        const uint4 b0 = *(const uint4*)(bG + k0);
        __syncthreads();
        *(uint4*)&As[t * 8]        = a0;
        *(uint4*)&As[2048 + t * 8] = a1;
        *(uint4*)&Bs[t * 8]        = b0;
        __syncthreads();
        const bf16x8 af0 = *(const bf16x8*)&As[aOff0];
        const bf16x8 af1 = *(const bf16x8*)&As[aOff1];
#pragma unroll
        for (int nt = 0; nt < 4; ++nt) {
            const bf16x8 bf = *(const bf16x8*)&Bs[bOff + nt * 512];
            acc[0][nt] = __builtin_amdgcn_mfma_f32_16x16x32_bf16(af0, bf, acc[0][nt], 0, 0, 0);
            acc[1][nt] = __builtin_amdgcn_mfma_f32_16x16x32_bf16(af1, bf, acc[1][nt], 0, 0, 0);
        }
    }
    // C/D: col = l16, row = quad*4 + r
    const int rowBase = m0 + wave * 32;
#pragma unroll
    for (int mt = 0; mt < 2; ++mt) {
#pragma unroll
        for (int nt = 0; nt < 4; ++nt) {
            const int col = n0 + nt * 16 + l16;
#pragma unroll
            for (int r = 0; r < 4; ++r) {
                const int row = rowBase + mt * 16 + quad * 4 + r;
                C[(size_t)row * Nc + col] = f2bf(acc[mt][nt][r]);
            }
        }
    }
}

// ---------- per-node attention scores s,d : [N,H], h is bf16 ----------
template <int H>
__global__ __launch_bounds__(128) void scores_kernel(
    const ushort* __restrict__ h, const float* __restrict__ a_src,
    const float* __restrict__ a_dst, float* __restrict__ s,
    float* __restrict__ d) {
    const int n = blockIdx.x, t = threadIdx.x;
    if (t < 32 * H) {
        const int head = t >> 5;
        const int c0 = (t & 31) * 4;
        const ushort4 hv = *(const ushort4*)&h[(size_t)n * (H * 128) + head * 128 + c0];
        const float4 as = *(const float4*)&a_src[head * 128 + c0];
        const float4 ad = *(const float4*)&a_dst[head * 128 + c0];
        const float h0 = bf2f(hv.x), h1 = bf2f(hv.y), h2 = bf2f(hv.z), h3 = bf2f(hv.w);
        float ps = h0 * as.x + h1 * as.y + h2 * as.z + h3 * as.w;
        float pd = h0 * ad.x + h1 * ad.y + h2 * ad.z + h3 * ad.w;
#pragma unroll
        for (int m = 16; m >= 1; m >>= 1) {
            ps += __shfl_xor(ps, m, 32);
            pd += __shfl_xor(pd, m, 32);
        }
        if ((t & 31) == 0) {
            s[n * H + head] = ps;
            d[n * H + head] = pd;
        }
    }
}

// ---------- CSR build ----------
__global__ void edge_hist(const int* __restrict__ ei, int E, int* __restrict__ cnt) {
    const int k = blockIdx.x * blockDim.x + threadIdx.x;
    const int ET = E + N_NODES;
    if (k < ET) {
        const int dstn = (k < E) ? ei[E + k] : (k - E);
        atomicAdd(&cnt[dstn], 1);
    }
}

// 3-phase scan: phase1 per-block (1024 elems) inclusive scan + block sums
__global__ __launch_bounds__(256) void scan_phase1(
    const int* __restrict__ cnt, int* __restrict__ incl,
    int* __restrict__ bsum, int n) {
    __shared__ int sh[256];
    const int b = blockIdx.x, t = threadIdx.x;
    const int i0 = b * 1024 + t * 4;
    int v[4]; int sum = 0;
#pragma unroll
    for (int k = 0; k < 4; ++k) {
        v[k] = (i0 + k < n) ? cnt[i0 + k] : 0;
        sum += v[k];
    }
    sh[t] = sum;
    __syncthreads();
    for (int off = 1; off < 256; off <<= 1) {
        const int a = (t >= off) ? sh[t - off] : 0;
        __syncthreads();
        sh[t] += a;
        __syncthreads();
    }
    int run = sh[t] - sum;   // exclusive prefix for this thread's 4 elems
#pragma unroll
    for (int k = 0; k < 4; ++k) {
        run += v[k];
        if (i0 + k < n) incl[i0 + k] = run;
    }
    if (t == 255) bsum[b] = sh[255];
}

__global__ void scan_phase2(int* __restrict__ bsum, int nb) {
    if (threadIdx.x == 0) {
        int run = 0;
        for (int i = 0; i < nb; ++i) { const int v = bsum[i]; bsum[i] = run; run += v; }
    }
}

__global__ void scan_phase3(const int* __restrict__ incl, const int* __restrict__ boffs,
                            int* __restrict__ rowptr, int* __restrict__ cursor, int n) {
    const int i = blockIdx.x * 256 + threadIdx.x;
    if (i < n) {
        rowptr[i + 1] = incl[i] + boffs[i >> 10];
        cursor[i] = (i == 0) ? 0 : (incl[i - 1] + boffs[(i - 1) >> 10]);
    }
    if (i == 0) rowptr[0] = 0;
}

__global__ void edge_scatter(const int* __restrict__ ei, int E,
                             int* __restrict__ cursor, int* __restrict__ col) {
    const int k = blockIdx.x * blockDim.x + threadIdx.x;
    const int ET = E + N_NODES;
    if (k < ET) {
        const int srcn = (k < E) ? ei[k] : (k - E);
        const int dstn = (k < E) ? ei[E + k] : (k - E);
        const int p = atomicAdd(&cursor[dstn], 1);
        col[p] = srcn;
    }
}

// ---------- aggregation: one block per destination node; max folded in (pass 1) ----------
template <int H>
__global__ __launch_bounds__(128) void aggregate(
    const ushort* __restrict__ h, const float* __restrict__ s,
    const float* __restrict__ dsc, const int* __restrict__ rowptr,
    const int* __restrict__ col, const float* __restrict__ bias,
    float* __restrict__ y) {
    constexpr int HC = H * 128;
    constexpr int VEC = HC / 128;          // 4 for H=4, 1 for H=1
    const int n = blockIdx.x, t = threadIdx.x;
    const int base = t * VEC;
    const int head = base >> 7;
    const float dn = dsc[n * H + head];
    const int rs = rowptr[n], re = rowptr[n + 1];
    // pass 1: segment max (every node has a self-loop, so re > rs)
    float em = -3.4e38f;
    for (int j = rs; j < re; ++j) {
        float e = s[col[j] * H + head] + dn;
        e = (e > 0.f) ? e : NEG * e;
        em = fmaxf(em, e);
    }
    // pass 2: exp-weighted accumulate
    float acc[VEC];
#pragma unroll
    for (int v = 0; v < VEC; ++v) acc[v] = 0.f;
    float den = 0.f;
    for (int j = rs; j < re; ++j) {
        const int srcn = col[j];
        float e = s[srcn * H + head] + dn;
        e = (e > 0.f) ? e : NEG * e;
        const float ex = __expf(e - em);
        den += ex;
        const ushort* hp = &h[(size_t)srcn * HC + base];
        if constexpr (VEC == 4) {
            const ushort4 hv = *(const ushort4*)hp;
            acc[0] += ex * bf2f(hv.x); acc[1] += ex * bf2f(hv.y);
            acc[2] += ex * bf2f(hv.z); acc[3] += ex * bf2f(hv.w);
        } else {
            acc[0] += ex * bf2f(hp[0]);
        }
    }
    const float inv = 1.f / (den + 1e-16f);
    if constexpr (H == 1) {
        y[(size_t)n * 128 + t] = acc[0] * inv + bias[t];
    } else {
        __shared__ float sh[512];
#pragma unroll
        for (int v = 0; v < VEC; ++v) sh[base + v] = acc[v] * inv;
        __syncthreads();
        if (t < 32) {
            const int c0 = t * 4;
#pragma unroll
            for (int v = 0; v < 4; ++v) {
                const float m = (sh[c0 + v] + sh[128 + c0 + v] +
                                 sh[256 + c0 + v] + sh[384 + c0 + v]) * 0.25f;
                y[(size_t)n * 128 + c0 + v] = m + bias[c0 + v];
            }
        }
    }
}

// ---------- BatchNorm ----------
__global__ __launch_bounds__(256) void bn_stats1(
    const float* __restrict__ y, float* __restrict__ partial, int nblocks) {
    const int b = blockIdx.x, t = threadIdx.x;
    const int c = t & 127;
    float sum = 0.f, sq = 0.f;
    for (int r = b * 2 + (t >> 7); r < N_NODES; r += nblocks * 2) {
        const float v = y[(size_t)r * 128 + c];
        sum += v;
        sq += v * v;
    }
    __shared__ float s1[256], s2[256];
    s1[t] = sum; s2[t] = sq;
    __syncthreads();
    if (t < 128) {
        partial[(size_t)b * 256 + c] = s1[t] + s1[t + 128];
        partial[(size_t)b * 256 + 128 + c] = s2[t] + s2[t + 128];
    }
}

__global__ __launch_bounds__(128) void bn_stats2(
    const float* __restrict__ partial, int nblocks,
    const float* __restrict__ gamma, const float* __restrict__ beta,
    float* __restrict__ stats) {
    const int c = threadIdx.x;
    float S = 0.f, Q = 0.f;
    for (int b = 0; b < nblocks; ++b) {
        S += partial[(size_t)b * 256 + c];
        Q += partial[(size_t)b * 256 + 128 + c];
    }
    const float mu = S / (float)N_NODES;
    const float var = Q / (float)N_NODES - mu * mu;
    const float sc = gamma[c] * rsqrtf(var + EPS_BN);
    stats[c] = sc;
    stats[128 + c] = beta[c] - mu * sc;
}

// BN + ReLU -> bf16 padded [M_PAD,128] (input to next layer's GEMM)
__global__ void bn_apply_bf16(const float* __restrict__ y,
                              const float* __restrict__ stats,
                              ushort* __restrict__ out) {
    const int i = blockIdx.x * 256 + threadIdx.x;
    const int e0 = i * 4;
    if (e0 >= M_PAD * 128) return;
    const int row = e0 >> 7;
    ushort4 o;
    if (row < N_NODES) {
        const float4 v = *(const float4*)&y[e0];
        const int c = e0 & 127;
        const float a = fmaxf(v.x * stats[c]     + stats[128 + c],     0.f);
        const float b = fmaxf(v.y * stats[c + 1] + stats[128 + c + 1], 0.f);
        const float cc = fmaxf(v.z * stats[c + 2] + stats[128 + c + 2], 0.f);
        const float d = fmaxf(v.w * stats[c + 3] + stats[128 + c + 3], 0.f);
        o = make_ushort4(f2bf(a), f2bf(b), f2bf(cc), f2bf(d));
    } else {
        o = make_ushort4(0, 0, 0, 0);
    }
    *(ushort4*)&out[e0] = o;
}

// final BN -> fp32 d_out (no relu)
__global__ void bn_apply_out(const float* __restrict__ y,
                             const float* __restrict__ stats,
                             float* __restrict__ out) {
    const int i = blockIdx.x * blockDim.x + threadIdx.x;
    if (i < N_NODES * 128) {
        const int c = i & 127;
        out[i] = y[i] * stats[c] + stats[128 + c];
    }
}

// ---------- launch ----------
extern "C" void kernel_launch(void* const* d_in, const int* in_sizes, int n_in,
                              void* d_out, int out_size, void* d_ws, size_t ws_size,
                              hipStream_t stream) {
    const float* x = (const float*)d_in[0];
    const int* ei = (const int*)d_in[1];
    const int E = in_sizes[1] / 2;
    const int ET = E + N_NODES;

    const float* W[3]    = {(const float*)d_in[2], (const float*)d_in[8],  (const float*)d_in[14]};
    const float* ASRC[3] = {(const float*)d_in[3], (const float*)d_in[9],  (const float*)d_in[15]};
    const float* ADST[3] = {(const float*)d_in[4], (const float*)d_in[10], (const float*)d_in[16]};
    const float* BIAS[3] = {(const float*)d_in[5], (const float*)d_in[11], (const float*)d_in[17]};
    const float* GAM[3]  = {(const float*)d_in[6], (const float*)d_in[12], (const float*)d_in[18]};
    const float* BET[3]  = {(const float*)d_in[7], (const float*)d_in[13], (const float*)d_in[19]};

    char* base = (char*)d_ws;
    auto alloc = [&](size_t bytes) {
        char* p = base;
        base += (bytes + 255) & ~(size_t)255;
        return p;
    };
    ushort* hbf    = (ushort*)alloc((size_t)M_PAD * 512 * 2);
    ushort* Xbf    = (ushort*)alloc((size_t)M_PAD * 256 * 2);
    ushort* Wt     = (ushort*)alloc((size_t)512 * 256 * 2);
    float*  y      = (float*)alloc((size_t)N_NODES * 128 * 4);
    float*  s      = (float*)alloc((size_t)N_NODES * 4 * 4);
    float*  dsc    = (float*)alloc((size_t)N_NODES * 4 * 4);
    int*    rowptr = (int*)alloc((size_t)(N_NODES + 1) * 4);
    int*    col    = (int*)alloc((size_t)ET * 4);
    int*    cnt    = (int*)alloc((size_t)N_NODES * 4);
    int*    cursor = (int*)alloc((size_t)N_NODES * 4);
    int*    incl   = (int*)alloc((size_t)N_NODES * 4);
    int*    bsum   = (int*)alloc((size_t)64 * 4);
    float*  partial = (float*)alloc((size_t)256 * 256 * 4);
    float*  stats   = (float*)alloc((size_t)256 * 4);
    if ((size_t)(base - (char*)d_ws) > ws_size) return;

    const int eb = (ET + 255) / 256;
    const int nScanB = (N_NODES + 1023) / 1024;

    // --- CSR build ---
    hipMemsetAsync(cnt, 0, (size_t)N_NODES * 4, stream);
    edge_hist<<<eb, 256, 0, stream>>>(ei, E, cnt);
    scan_phase1<<<nScanB, 256, 0, stream>>>(cnt, incl, bsum, N_NODES);
    scan_phase2<<<1, 64, 0, stream>>>(bsum, nScanB);
    scan_phase3<<<(N_NODES + 255) / 256, 256, 0, stream>>>(incl, bsum, rowptr, cursor, N_NODES);
    edge_scatter<<<eb, 256, 0, stream>>>(ei, E, cursor, col);

    // --- layer-0 input to bf16 (padded) ---
    conv_x<<<(M_PAD * 256 / 4 + 255) / 256, 256, 0, stream>>>(x, Xbf);

    const int Hs[3]  = {4, 4, 1};
    const int Kin[3] = {256, 128, 128};

    for (int L = 0; L < 3; ++L) {
        const int H = Hs[L], K = Kin[L], Nc = H * 128;

        convT<<<(K * Nc + 255) / 256, 256, 0, stream>>>(W[L], Wt, K, Nc);
        dim3 ggrid(Nc / 64, M_PAD / 128);
        gemm_bf16<<<ggrid, 256, 0, stream>>>(Xbf, Wt, hbf, K, Nc);

        if (H == 4) {
            scores_kernel<4><<<N_NODES, 128, 0, stream>>>(hbf, ASRC[L], ADST[L], s, dsc);
            aggregate<4><<<N_NODES, 128, 0, stream>>>(hbf, s, dsc, rowptr, col, BIAS[L], y);
        } else {
            scores_kernel<1><<<N_NODES, 128, 0, stream>>>(hbf, ASRC[L], ADST[L], s, dsc);
            aggregate<1><<<N_NODES, 128, 0, stream>>>(hbf, s, dsc, rowptr, col, BIAS[L], y);
        }

        bn_stats1<<<256, 256, 0, stream>>>(y, partial, 256);
        bn_stats2<<<1, 128, 0, stream>>>(partial, 256, GAM[L], BET[L], stats);

        if (L < 2) {
            bn_apply_bf16<<<(M_PAD * 128 / 4 + 255) / 256, 256, 0, stream>>>(y, stats, Xbf);
        } else {
            bn_apply_out<<<(N_NODES * 128 + 255) / 256, 256, 0, stream>>>(y, stats, (float*)d_out);
        }
    }
}